// Round 8
// baseline (138.143 us; speedup 1.0000x reference)
//
#include <hip/hip_runtime.h>
#include <hip/hip_bf16.h>

// LSTM_71382356459716 R16: unit-split -- 2 issue-independent waves per SIMD.
// R15 post-mortem: AGPR pin landed (VGPR 156->220, remat impossible) yet dur
// flat 59.0us -> L2-reload theory dead (reload was overlapped, not critical).
// Surviving facts: wall ~5100 cyc/step/SIMD, VALU issue ~2460 (VALUBusy 48%),
// rest = EXPOSED dependency latency (ds_read ~120cy, 3-deep MFMA, serial
// exp2->rcp->fma chains) because R13-R15 run exactly 1 wave/SIMD -- nothing
// fills the single wave's stalls. R10's lockstep-8 failure isn't a counter-
// example: need issue-INDEPENDENT waves, not more barrier-synced ones.
// R16: wave w in {0,1} owns M-tiles 8w..8w+7 (half the units) for the same
// 16 rows. Per-wave work halves, chip-wide issue CONSERVED, wave count
// doubles -> 2048 waves = 2/SIMD; each wave's stalls filled by the other
// (MFMA/VALU pipes co-schedule, m114). pi permutation keeps wave w's 8
// h-values contiguous (cols 16q+8w..+7) -> one b128 h-store per lane.
// One __syncthreads/step between 2 symmetric waves (cheap), A-frag asm pin
// kept (clobbers harmless now).
// Prediction: 59.7 -> 30-38us; VALUBusy 75-90%; MfmaUtil ~25%; Occ ~20%.
// Failure tells: flat+VALUBusy~48 -> pipe-bound stalls (profile trans);
// ~45us -> barrier phase-coupling, de-phase waves next.

namespace {
constexpr int B_TOT   = 16384;
constexpr int T_STEPS = 28;
constexpr int IN_DIM  = 28;
constexpr int HID     = 64;
constexpr int OUT_DIM = 10;
constexpr int ROWS    = 16;    // batch rows per block
constexpr int THREADS = 128;   // 2 waves; wave w owns M-tiles 8w..8w+7
constexpr int KP      = 104;   // row stride in shorts (208 B = 13*16B)
constexpr int XROW    = T_STEPS * IN_DIM;  // 784 floats per batch row
constexpr int NFRAG   = 16 * 3;            // 16 Mtiles * 3 kchunks
constexpr int WS_ELEMS = NFRAG * 64 * 8;   // 24576 bf16 = 48 KB
}

typedef __attribute__((ext_vector_type(8))) short short8v;   // 8 bf16
typedef __attribute__((ext_vector_type(4))) short short4v;
typedef __attribute__((ext_vector_type(4))) float float4v;

__device__ __forceinline__ short f2bf_cold(float f) {
  union { float f; unsigned u; } v; v.f = f;
  unsigned r = v.u + 0x7FFFu + ((v.u >> 16) & 1u);
  return (short)(r >> 16);
}
__device__ __forceinline__ float bf2f(short s) {
  union { unsigned u; float f; } v; v.u = ((unsigned)(unsigned short)s) << 16;
  return v.f;
}
__device__ __forceinline__ unsigned pk2(float a, float b) {  // 2xf32->bf16x2
  __hip_bfloat162 h = __float22bfloat162_rn(float2{a, b});
  union { __hip_bfloat162 h; unsigned u; } cv; cv.h = h; return cv.u;
}

// ---- setup: permute weights+bias into MFMA A-frag order (runs every call) --
// ws layout: frag f = mt*3 + kc, lane l, elem j:
//   ws[(f*64 + l)*8 + j] = bf16 of A[m=16*mt+(l&15)][k=kc*32+(l>>4)*8+j]
// gate row g = (m&3)*64 + (m>>2); k<28 -> W_ih, k==28 -> b_ih+b_hh,
// 29..31 -> 0, k>=32 -> W_hh[:, u(k-32)] where stored h col c holds unit
// u(c) = 4*(c&15) + (c>>4)   [pi: lane (q,l15) of wave w writes units
// 4(8w+i)+q at cols 16q+8w+i, i=0..7 contiguous].
// All values pre-scaled by -log2(e) (gates i,f,o) / -2*log2(e) (gate g).
__global__ void lstm_prep(const float* __restrict__ W_ih,
                          const float* __restrict__ W_hh,
                          const float* __restrict__ b_ih,
                          const float* __restrict__ b_hh,
                          unsigned short* __restrict__ ws) {
  int idx = blockIdx.x * blockDim.x + threadIdx.x;
  if (idx >= WS_ELEMS) return;
  int j  = idx & 7;
  int l  = (idx >> 3) & 63;
  int fk = idx >> 9;            // mt*3 + kc
  int kc = fk % 3;
  int mt = fk / 3;
  int m  = 16 * mt + (l & 15);
  int unit = m >> 2, type = m & 3;
  int g  = type * 64 + unit;
  int k  = kc * 32 + (l >> 4) * 8 + j;
  float v = 0.0f;
  if (k < IN_DIM)        v = W_ih[g * IN_DIM + k];
  else if (k == IN_DIM)  v = b_ih[g] + b_hh[g];
  else if (k >= 32) {
    int c = k - 32;
    int u = 4 * (c & 15) + (c >> 4);   // pi
    v = W_hh[g * HID + u];
  }
  v *= (type == 2) ? -2.8853900817779268f : -1.4426950408889634f;
  ws[idx] = (unsigned short)f2bf_cold(v);
}

__global__ __attribute__((amdgpu_flat_work_group_size(THREADS, THREADS),
                          amdgpu_waves_per_eu(2, 2)))
void lstm_wave(const float* __restrict__ x,
               const unsigned short* __restrict__ wfrag,
               const float* __restrict__ W_fc,
               const float* __restrict__ b_fc, float* __restrict__ out) {
  // [buf][row][k]: cols 0..27 x, 28 = 1.0 (bias), 32..95 h (pi-permuted)
  __shared__ __align__(16) short hs[2][ROWS][KP];

  const int tid  = threadIdx.x;
  const int lane = tid & 63;
  const int w    = tid >> 6;      // wave 0..1 -> M-tiles 8w..8w+7
  const int l15  = lane & 15;
  const int q    = lane >> 4;     // 0..3
  const int b0   = blockIdx.x * ROWS;

  // ---- stationary A: this wave's 8 M-tiles, 24 coalesced 16B loads, pinned
  // into AGPRs via opaque asm (remat impossible) ----------------------------
  short8v a[8][3];
#pragma unroll
  for (int i = 0; i < 8; ++i)
#pragma unroll
    for (int kc = 0; kc < 3; ++kc)
      a[i][kc] = *(const short8v*)&wfrag[((((8 * w + i) * 3) + kc) * 64 + lane) * 8];
#pragma unroll
  for (int i = 0; i < 8; ++i)
#pragma unroll
    for (int kc = 0; kc < 3; ++kc)
      asm volatile("" : "+a"(a[i][kc]));   // pin: AGPR-resident, opaque

  // zero both buffers (832 short4 slots), then the constant bias column
  {
    short4v z4 = {0, 0, 0, 0};
    for (int idx = tid; idx < 2 * ROWS * KP / 4; idx += THREADS)
      ((short4v*)&hs[0][0][0])[idx] = z4;
  }
  __syncthreads();
  if (tid < 2 * ROWS)   // buf = tid>>4, row = tid&15
    hs[tid >> 4][tid & 15][IN_DIM] = (short)0x3F80;  // bf16 1.0

  // ---- x staging: 112 float4-slots; threads 0..111 take one each ----------
  const bool stager = (tid < 112);
  const int  sr = tid / 7, sc = tid - 7 * (tid / 7);
  const float* xptr = x + (size_t)(b0 + (stager ? sr : 0)) * XROW + sc * 4;

  float4 xfly = {0.f, 0.f, 0.f, 0.f};
  if (stager) {
    float4 x0 = *(const float4*)xptr;
    short4v sv;
    unsigned plo = pk2(x0.x, x0.y), phi = pk2(x0.z, x0.w);
    sv[0] = (short)(plo & 0xFFFF); sv[1] = (short)(plo >> 16);
    sv[2] = (short)(phi & 0xFFFF); sv[3] = (short)(phi >> 16);
    *(short4v*)&hs[0][sr][sc * 4] = sv;
    xfly = *(const float4*)(xptr + 1 * IN_DIM);   // x_1, consumed at t=0
  }
  __syncthreads();

  float c_state[8];
#pragma unroll
  for (int i = 0; i < 8; ++i) c_state[i] = 0.f;

  for (int t = 0; t < T_STEPS; ++t) {
    const int cur = t & 1, nxt = cur ^ 1;

    // B-frags: lane holds B[k = kc*32 + q*8 + j][n = l15]
    short8v bf0 = *(const short8v*)&hs[cur][l15][q * 8];
    short8v bf1 = *(const short8v*)&hs[cur][l15][32 + q * 8];
    short8v bf2 = *(const short8v*)&hs[cur][l15][64 + q * 8];

    // store x_{t+1} (loaded a full step ago), issue load of x_{t+2}
    if (stager) {
      if (t + 1 < T_STEPS) {
        short4v sv;
        unsigned plo = pk2(xfly.x, xfly.y), phi = pk2(xfly.z, xfly.w);
        sv[0] = (short)(plo & 0xFFFF); sv[1] = (short)(plo >> 16);
        sv[2] = (short)(phi & 0xFFFF); sv[3] = (short)(phi >> 16);
        *(short4v*)&hs[nxt][sr][sc * 4] = sv;
      }
      if (t + 2 < T_STEPS)
        xfly = *(const float4*)(xptr + (t + 2) * IN_DIM);
    }

    // this wave's 8 M-tiles x 3 k-chunks: 24 MFMA, 8 independent chains
    const float4v zero4 = {0.f, 0.f, 0.f, 0.f};
    float4v acc[8];
#pragma unroll
    for (int i = 0; i < 8; ++i)
      acc[i] = __builtin_amdgcn_mfma_f32_16x16x32_bf16(a[i][0], bf0, zero4, 0, 0, 0);
#pragma unroll
    for (int i = 0; i < 8; ++i)
      acc[i] = __builtin_amdgcn_mfma_f32_16x16x32_bf16(a[i][1], bf1, acc[i], 0, 0, 0);
#pragma unroll
    for (int i = 0; i < 8; ++i)
      acc[i] = __builtin_amdgcn_mfma_f32_16x16x32_bf16(a[i][2], bf2, acc[i], 0, 0, 0);

    // activations: lane (q,l15) owns unit 4(8w+i)+q, row l15; regs = i,f,g,o.
    // exp scales pre-folded -> bare exp2. 8 independent chains.
    float hv[8];
#pragma unroll
    for (int i = 0; i < 8; ++i) {
      float4v g4 = acc[i];
      float Ei = __builtin_amdgcn_exp2f(g4[0]);
      float Ef = __builtin_amdgcn_exp2f(g4[1]);
      float Eg = __builtin_amdgcn_exp2f(g4[2]);
      float Eo = __builtin_amdgcn_exp2f(g4[3]);
      float di = 1.0f + Ei, df = 1.0f + Ef;
      float r1 = __builtin_amdgcn_rcpf(di * df);
      float iv = r1 * df;
      float fv = r1 * di;
      float gv = fmaf(2.0f, __builtin_amdgcn_rcpf(1.0f + Eg), -1.0f);
      float cn = fmaf(fv, c_state[i], iv * gv);
      c_state[i] = cn;
      float ct = fminf(fmaxf(cn, -15.0f), 15.0f);   // tanh saturated beyond
      float Ec = __builtin_amdgcn_exp2f(-2.8853900817779268f * ct);
      float dn = 1.0f + Eo, dc = 1.0f + Ec;
      float r2 = __builtin_amdgcn_rcpf(dn * dc);
      float ov = r2 * dc;
      float tc = fmaf(2.0f * r2, dn, -1.0f);
      hv[i] = ov * tc;
    }

    // pack 8 bf16 (unit 4(8w+i)+q at col 16q+8w+i) -> one b128 store
    union { unsigned u[4]; short8v s; } uh;
#pragma unroll
    for (int p = 0; p < 4; ++p) uh.u[p] = pk2(hv[2 * p], hv[2 * p + 1]);
    *(short8v*)&hs[nxt][l15][32 + 16 * q + 8 * w] = uh.s;

    __syncthreads();
  }

  // ---- FC epilogue: final h in hs[0] (t=27 wrote nxt=0); col c = unit u(c) -
  // 128 threads: row er = tid>>3, output eo = tid&7 (+8 if eo<2)
  {
    const int er = tid >> 3;       // 0..15
    const int eo = tid & 7;        // 0..7
    float s0a = b_fc[eo];
    float s2a = (eo < 2) ? b_fc[eo + 8] : 0.f;
#pragma unroll
    for (int c = 0; c < HID; ++c) {
      float hb = bf2f(hs[0][er][32 + c]);
      int u = 4 * (c & 15) + (c >> 4);
      s0a = fmaf(hb, W_fc[eo * HID + u], s0a);
      if (eo < 2) s2a = fmaf(hb, W_fc[(eo + 8) * HID + u], s2a);
    }
    float* orow = out + (size_t)(b0 + er) * OUT_DIM;
    orow[eo] = s0a;
    if (eo < 2) orow[eo + 8] = s2a;
  }
}

extern "C" void kernel_launch(void* const* d_in, const int* in_sizes, int n_in,
                              void* d_out, int out_size, void* d_ws, size_t ws_size,
                              hipStream_t stream) {
  const float* x    = (const float*)d_in[0];
  const float* W_ih = (const float*)d_in[1];
  const float* W_hh = (const float*)d_in[2];
  const float* b_ih = (const float*)d_in[3];
  const float* b_hh = (const float*)d_in[4];
  const float* W_fc = (const float*)d_in[5];
  const float* b_fc = (const float*)d_in[6];
  float* out = (float*)d_out;
  unsigned short* ws = (unsigned short*)d_ws;   // 48 KB frag-ordered weights

  lstm_prep<<<(WS_ELEMS + 255) / 256, 256, 0, stream>>>(W_ih, W_hh, b_ih, b_hh, ws);

  dim3 grid(B_TOT / ROWS);   // 1024 blocks x 2 waves = 2048 waves = 2/SIMD
  dim3 block(THREADS);
  lstm_wave<<<grid, block, 0, stream>>>(x, ws, W_fc, b_fc, out);
}